// Round 1
// baseline (303.202 us; speedup 1.0000x reference)
//
#include <hip/hip_runtime.h>
#include <math.h>

// Problem constants (from reference: B=8192, D=4096)
#define B_ROWS 8192
#define D_DIM  4096

// Zero the f64 accumulator in workspace (d_ws is re-poisoned to 0xAA before
// every timed launch, so this must run each call).
__global__ void mahal_init_kernel(double* __restrict__ acc) {
    if (threadIdx.x == 0 && blockIdx.x == 0) *acc = 0.0;
}

// One block per row. Each thread: 4 iterations of float4 loads (coalesced),
// mask by j < n_i, accumulate sum(d^2) and sum(d_j * d_{j+1}).
__global__ __launch_bounds__(256) void mahal_main_kernel(
    const float* __restrict__ y_true,
    const float* __restrict__ y_pred,
    const float* __restrict__ param,
    const int*   __restrict__ n,
    double*      __restrict__ acc)
{
    const int row = blockIdx.x;
    const int tid = threadIdx.x;
    const int ni  = n[row];

    const float* yt = y_true + (size_t)row * D_DIM;
    const float* yp = y_pred + (size_t)row * D_DIM;

    float sum_sq  = 0.f;
    float sum_adj = 0.f;

    // D = 4096 = 4 iters * 256 threads * 4 floats
    #pragma unroll
    for (int it = 0; it < D_DIM / (256 * 4); ++it) {
        const int j = it * (256 * 4) + tid * 4;
        const float4 t = *reinterpret_cast<const float4*>(yt + j);
        const float4 p = *reinterpret_cast<const float4*>(yp + j);
        const float d0 = (j + 0 < ni) ? (t.x - p.x) : 0.f;
        const float d1 = (j + 1 < ni) ? (t.y - p.y) : 0.f;
        const float d2 = (j + 2 < ni) ? (t.z - p.z) : 0.f;
        const float d3 = (j + 3 < ni) ? (t.w - p.w) : 0.f;
        // neighbor element from the next vector; redundant scalar load is an
        // L1/L2 hit (neighbor lane just fetched that line). Guarded: j+4 < ni
        // implies j+4 <= D-1, so never OOB.
        const float d4 = (j + 4 < ni) ? (yt[j + 4] - yp[j + 4]) : 0.f;

        sum_sq  += d0 * d0 + d1 * d1 + d2 * d2 + d3 * d3;
        sum_adj += d0 * d1 + d1 * d2 + d2 * d3 + d3 * d4;
    }

    // Wave (64-lane) shuffle reduction
    #pragma unroll
    for (int off = 32; off > 0; off >>= 1) {
        sum_sq  += __shfl_down(sum_sq,  off, 64);
        sum_adj += __shfl_down(sum_adj, off, 64);
    }

    __shared__ float s_sq[4];
    __shared__ float s_adj[4];
    const int wave = tid >> 6;
    if ((tid & 63) == 0) { s_sq[wave] = sum_sq; s_adj[wave] = sum_adj; }
    __syncthreads();

    if (tid == 0) {
        const float tot_sq  = s_sq[0] + s_sq[1] + s_sq[2] + s_sq[3];
        const float tot_adj = s_adj[0] + s_adj[1] + s_adj[2] + s_adj[3];
        const float x    = param[0];
        const float rho  = 2.0f * (1.0f / (1.0f + expf(-x))) - 1.0f;  // 2*sigmoid-1
        const float coef = -rho / (1.0f + rho * rho);
        const double quad = (double)tot_sq + 2.0 * (double)coef * (double)tot_adj;
        atomicAdd(acc, quad / ((double)ni * (double)B_ROWS));
    }
}

__global__ void mahal_final_kernel(const double* __restrict__ acc,
                                   float* __restrict__ out) {
    if (threadIdx.x == 0 && blockIdx.x == 0) *out = (float)(*acc);
}

extern "C" void kernel_launch(void* const* d_in, const int* in_sizes, int n_in,
                              void* d_out, int out_size, void* d_ws, size_t ws_size,
                              hipStream_t stream) {
    const float* y_true = (const float*)d_in[0];
    const float* y_pred = (const float*)d_in[1];
    const float* param  = (const float*)d_in[2];
    const int*   n      = (const int*)d_in[3];
    float* out = (float*)d_out;
    double* acc = (double*)d_ws;

    mahal_init_kernel<<<1, 64, 0, stream>>>(acc);
    mahal_main_kernel<<<B_ROWS, 256, 0, stream>>>(y_true, y_pred, param, n, acc);
    mahal_final_kernel<<<1, 64, 0, stream>>>(acc, out);
}

// Round 2
// 249.381 us; speedup vs baseline: 1.2158x; 1.2158x over previous
//
#include <hip/hip_runtime.h>
#include <math.h>

// Problem constants (from reference: B=8192, D=4096)
#define B_ROWS 8192
#define D_DIM  4096

// One block (256 threads) per row. Each thread owns 4 elements per tile,
// 4 tiles of 1024 elements cover D=4096. Loads are predicated on j < n_i
// (masked-out tail is never fetched -> ~halves HBM traffic for uniform n),
// and all 8 float4 loads are issued into registers before first use for ILP.
// Neighbor element d_{j+4} (needed for the superdiagonal dot) comes from an
// LDS stage of each thread's d0 -- no redundant global loads.
__global__ __launch_bounds__(256) void mahal_main_kernel(
    const float* __restrict__ y_true,
    const float* __restrict__ y_pred,
    const int*   __restrict__ n,
    float2*      __restrict__ partial)
{
    const int row = blockIdx.x;
    const int tid = threadIdx.x;
    const int ni  = n[row];

    const float4* yt4 = reinterpret_cast<const float4*>(y_true + (size_t)row * D_DIM);
    const float4* yp4 = reinterpret_cast<const float4*>(y_pred + (size_t)row * D_DIM);

    // Issue all loads up front (exec-masked: lanes with j >= ni fetch nothing).
    float4 t[4], p[4];
    #pragma unroll
    for (int it = 0; it < 4; ++it) {
        const int j = (it << 10) + (tid << 2);
        t[it] = make_float4(0.f, 0.f, 0.f, 0.f);
        p[it] = make_float4(0.f, 0.f, 0.f, 0.f);
        if (j < ni) {
            t[it] = yt4[it * 256 + tid];
            p[it] = yp4[it * 256 + tid];
        }
    }

    // Masked differences; stage d0 of each tile in LDS for neighbor access.
    __shared__ float s0[4][257];
    float d[4][4];
    #pragma unroll
    for (int it = 0; it < 4; ++it) {
        const int j = (it << 10) + (tid << 2);
        d[it][0] = (j + 0 < ni) ? (t[it].x - p[it].x) : 0.f;
        d[it][1] = (j + 1 < ni) ? (t[it].y - p[it].y) : 0.f;
        d[it][2] = (j + 2 < ni) ? (t[it].z - p[it].z) : 0.f;
        d[it][3] = (j + 3 < ni) ? (t[it].w - p[it].w) : 0.f;
        s0[it][tid] = d[it][0];
    }
    __syncthreads();

    float sum_sq = 0.f, sum_adj = 0.f;
    #pragma unroll
    for (int it = 0; it < 4; ++it) {
        // d_{j+4}: next thread's d0 (same tile), or next tile's thread-0 d0.
        float nb;
        if (tid < 255) nb = s0[it][tid + 1];
        else           nb = (it < 3) ? s0[it + 1][0] : 0.f;
        sum_sq  += d[it][0] * d[it][0] + d[it][1] * d[it][1]
                 + d[it][2] * d[it][2] + d[it][3] * d[it][3];
        sum_adj += d[it][0] * d[it][1] + d[it][1] * d[it][2]
                 + d[it][2] * d[it][3] + d[it][3] * nb;
    }

    // Wave (64-lane) shuffle reduction, then cross-wave via LDS.
    #pragma unroll
    for (int off = 32; off > 0; off >>= 1) {
        sum_sq  += __shfl_down(sum_sq,  off, 64);
        sum_adj += __shfl_down(sum_adj, off, 64);
    }

    __shared__ float r_sq[4], r_adj[4];
    const int wave = tid >> 6;
    if ((tid & 63) == 0) { r_sq[wave] = sum_sq; r_adj[wave] = sum_adj; }
    __syncthreads();

    if (tid == 0) {
        const float inv_n = 1.0f / (float)ni;
        const float ssq   = r_sq[0] + r_sq[1] + r_sq[2] + r_sq[3];
        const float sadj  = r_adj[0] + r_adj[1] + r_adj[2] + r_adj[3];
        partial[row] = make_float2(ssq * inv_n, sadj * inv_n);
    }
}

// Reduce 8192 float2 partials (as 4096 float4), apply coef, write the scalar.
__global__ __launch_bounds__(256) void mahal_final_kernel(
    const float2* __restrict__ partial,
    const float*  __restrict__ param,
    float*        __restrict__ out)
{
    const int tid = threadIdx.x;
    const float4* p4 = reinterpret_cast<const float4*>(partial);  // 4096 float4
    double s1 = 0.0, s2 = 0.0;
    #pragma unroll
    for (int it = 0; it < 16; ++it) {
        const float4 v = p4[it * 256 + tid];
        s1 += (double)v.x + (double)v.z;
        s2 += (double)v.y + (double)v.w;
    }
    #pragma unroll
    for (int off = 32; off > 0; off >>= 1) {
        s1 += __shfl_down(s1, off, 64);
        s2 += __shfl_down(s2, off, 64);
    }
    __shared__ double w1[4], w2[4];
    const int wave = tid >> 6;
    if ((tid & 63) == 0) { w1[wave] = s1; w2[wave] = s2; }
    __syncthreads();
    if (tid == 0) {
        const double S1 = w1[0] + w1[1] + w1[2] + w1[3];
        const double S2 = w2[0] + w2[1] + w2[2] + w2[3];
        const float x    = param[0];
        const float rho  = 2.0f * (1.0f / (1.0f + expf(-x))) - 1.0f;  // 2*sigmoid-1
        const float coef = -rho / (1.0f + rho * rho);
        *out = (float)((S1 + 2.0 * (double)coef * S2) / (double)B_ROWS);
    }
}

extern "C" void kernel_launch(void* const* d_in, const int* in_sizes, int n_in,
                              void* d_out, int out_size, void* d_ws, size_t ws_size,
                              hipStream_t stream) {
    const float* y_true = (const float*)d_in[0];
    const float* y_pred = (const float*)d_in[1];
    const float* param  = (const float*)d_in[2];
    const int*   n      = (const int*)d_in[3];
    float* out = (float*)d_out;
    float2* partial = (float2*)d_ws;  // 8192 float2 = 64 KB, fully written each call

    mahal_main_kernel<<<B_ROWS, 256, 0, stream>>>(y_true, y_pred, n, partial);
    mahal_final_kernel<<<1, 256, 0, stream>>>(partial, param, out);
}

// Round 4
// 248.836 us; speedup vs baseline: 1.2185x; 1.0022x over previous
//
#include <hip/hip_runtime.h>
#include <math.h>

// Problem constants (from reference: B=8192, D=4096)
#define B_ROWS 8192
#define D_DIM  4096

// One block (256 threads = 4 waves) per row. Wave w owns the contiguous
// span [w*1024, (w+1)*1024); within it, chunk q (0..3) element = q*256+lane*4.
// All 8 float4 loads are issued before first use; loads are predicated on
// j < n_i so the masked tail is never fetched. The superdiagonal neighbor
// d_{j+4} is obtained via __shfl_down(d0, 1) (next lane, same chunk); lane 63
// takes a broadcast of lane0's d0 of chunk q+1, and for its last chunk a
// 2-dword predicated global load of the next wave's first element (L1-hit).
// NO mid-kernel barrier -> no vmcnt(0) drain until the final 4-entry LDS
// reduction at the very end.
__global__ __launch_bounds__(256) void mahal_main_kernel(
    const float* __restrict__ y_true,
    const float* __restrict__ y_pred,
    const float* __restrict__ param,
    const int*   __restrict__ n,
    float*       __restrict__ partial)
{
    const int row  = blockIdx.x;
    const int tid  = threadIdx.x;
    const int lane = tid & 63;
    const int w    = tid >> 6;
    const int ni   = n[row];

    const float* yt = y_true + (size_t)row * D_DIM;
    const float* yp = y_pred + (size_t)row * D_DIM;
    const int base = (w << 10) + (lane << 2);

    // Issue all loads up front (exec-masked: fully-masked waves skip cleanly).
    float4 t[4], p[4];
    #pragma unroll
    for (int q = 0; q < 4; ++q) {
        const int j = base + (q << 8);
        t[q] = make_float4(0.f, 0.f, 0.f, 0.f);
        p[q] = make_float4(0.f, 0.f, 0.f, 0.f);
        if (j < ni) {
            t[q] = *reinterpret_cast<const float4*>(yt + j);
            p[q] = *reinterpret_cast<const float4*>(yp + j);
        }
    }
    // Wave-boundary neighbor: first element of the next wave's span.
    // e in {1024,2048,3072} (wave 3 -> e=4096 >= ni always -> stays 0, which
    // also matches the reference's zero-pad at the row end).
    float bnd = 0.f;
    if (lane == 63) {
        const int e = (w + 1) << 10;
        if (e < ni) bnd = yt[e] - yp[e];
    }

    // Masked differences (all in registers, compile-time indexed).
    float d[4][4];
    #pragma unroll
    for (int q = 0; q < 4; ++q) {
        const int j = base + (q << 8);
        d[q][0] = (j + 0 < ni) ? (t[q].x - p[q].x) : 0.f;
        d[q][1] = (j + 1 < ni) ? (t[q].y - p[q].y) : 0.f;
        d[q][2] = (j + 2 < ni) ? (t[q].z - p[q].z) : 0.f;
        d[q][3] = (j + 3 < ni) ? (t[q].w - p[q].w) : 0.f;
    }

    float ssq = 0.f, sadj = 0.f;
    #pragma unroll
    for (int q = 0; q < 4; ++q) {
        // Neighbor of this thread's d3: next lane's d0 (same chunk); lane 63:
        // lane0's d0 of chunk q+1 (broadcast), or the wave-boundary value.
        float nb = __shfl_down(d[q][0], 1, 64);
        const float bq = (q < 3) ? __shfl(d[q + 1 < 4 ? q + 1 : 3][0], 0, 64) : bnd;
        if (lane == 63) nb = bq;
        ssq  += d[q][0] * d[q][0] + d[q][1] * d[q][1]
              + d[q][2] * d[q][2] + d[q][3] * d[q][3];
        sadj += d[q][0] * d[q][1] + d[q][1] * d[q][2]
              + d[q][2] * d[q][3] + d[q][3] * nb;
    }

    // Fold coef in now (param is a uniform scalar load, L2-hit) so the
    // reduction carries a single value.
    const float x    = param[0];
    const float rho  = 2.0f * (1.0f / (1.0f + expf(-x))) - 1.0f;  // 2*sigmoid-1
    const float coef = -rho / (1.0f + rho * rho);
    float quad = ssq + 2.0f * coef * sadj;

    // Wave butterfly, then 4-entry LDS cross-wave sum (single end barrier).
    #pragma unroll
    for (int off = 32; off > 0; off >>= 1)
        quad += __shfl_down(quad, off, 64);

    __shared__ float r[4];
    if (lane == 0) r[w] = quad;
    __syncthreads();
    if (tid == 0)
        partial[row] = (r[0] + r[1] + r[2] + r[3]) / (float)ni;
}

// Sum 8192 per-row values (as 2048 float4) in double, divide by B, write out.
__global__ __launch_bounds__(256) void mahal_final_kernel(
    const float* __restrict__ partial,
    float*       __restrict__ out)
{
    const int tid = threadIdx.x;
    const float4* p4 = reinterpret_cast<const float4*>(partial);  // 2048 float4
    double s = 0.0;
    #pragma unroll
    for (int it = 0; it < 8; ++it) {
        const float4 v = p4[it * 256 + tid];
        s += (double)v.x + (double)v.y + (double)v.z + (double)v.w;
    }
    #pragma unroll
    for (int off = 32; off > 0; off >>= 1)
        s += __shfl_down(s, off, 64);
    __shared__ double wsum[4];
    if ((tid & 63) == 0) wsum[tid >> 6] = s;
    __syncthreads();
    if (tid == 0)
        *out = (float)((wsum[0] + wsum[1] + wsum[2] + wsum[3]) / (double)B_ROWS);
}

extern "C" void kernel_launch(void* const* d_in, const int* in_sizes, int n_in,
                              void* d_out, int out_size, void* d_ws, size_t ws_size,
                              hipStream_t stream) {
    const float* y_true = (const float*)d_in[0];
    const float* y_pred = (const float*)d_in[1];
    const float* param  = (const float*)d_in[2];
    const int*   n      = (const int*)d_in[3];
    float* out = (float*)d_out;
    float* partial = (float*)d_ws;  // 8192 floats = 32 KB, fully written each call

    mahal_main_kernel<<<B_ROWS, 256, 0, stream>>>(y_true, y_pred, param, n, partial);
    mahal_final_kernel<<<1, 256, 0, stream>>>(partial, out);
}